// Round 1
// baseline (3892.248 us; speedup 1.0000x reference)
//
#include <hip/hip_runtime.h>
#include <math.h>

// Problem constants (from reference): C=64 channels, NT=3 ntype columns.
#define CCH 64

__device__ __forceinline__ void atomicMaxF(float* addr, float v) {
    // Standard float-max-via-int trick (valid for non-NaN, init = -inf):
    // nonnegative floats ordered as signed ints (use atomicMax),
    // negative floats reverse-ordered as unsigned ints (use atomicMin).
    if (v >= 0.0f) {
        atomicMax((int*)addr, __float_as_int(v));
    } else {
        atomicMin((unsigned int*)addr, __float_as_uint(v));
    }
}

__global__ __launch_bounds__(256) void fill_neginf_kernel(float4* out, int n4) {
    int i = blockIdx.x * blockDim.x + threadIdx.x;
    int stride = gridDim.x * blockDim.x;
    const float4 v = make_float4(-INFINITY, -INFINITY, -INFINITY, -INFINITY);
    for (; i < n4; i += stride) out[i] = v;
}

// One thread handles 4 channels (float4) of one edge; 16 threads per edge.
__global__ __launch_bounds__(256) void scatter_max_kernel(
        const float4* __restrict__ feat4,   // [N_IN, 16] float4
        const int*    __restrict__ src,     // [E]
        const int*    __restrict__ tgt,     // [E]
        const int*    __restrict__ ntypes,  // [E, 3]
        float*        __restrict__ out,     // [N_OUT, 64]
        int E) {
    int gid = blockIdx.x * blockDim.x + threadIdx.x;
    int e = gid >> 4;
    int q = gid & 15;
    if (e >= E) return;

    // mask: all 3 ntypes >= 0  <=>  OR of them has sign bit clear
    int n0 = ntypes[e * 3 + 0];
    int n1 = ntypes[e * 3 + 1];
    int n2 = ntypes[e * 3 + 2];
    if ((n0 | n1 | n2) < 0) return;

    int t = tgt[e];
    int s = src[e];
    float4 f = feat4[(size_t)t * 16 + q];
    float* o = out + (size_t)s * CCH + q * 4;
    atomicMaxF(o + 0, f.x);
    atomicMaxF(o + 1, f.y);
    atomicMaxF(o + 2, f.z);
    atomicMaxF(o + 3, f.w);
}

__global__ __launch_bounds__(256) void finalize_kernel(
        float4* out, int n4, const int* feat_depth, float* scalar_slot) {
    int i = blockIdx.x * blockDim.x + threadIdx.x;
    int stride = gridDim.x * blockDim.x;
    for (; i < n4; i += stride) {
        float4 v = out[i];
        v.x = (v.x == -INFINITY) ? 0.0f : v.x;
        v.y = (v.y == -INFINITY) ? 0.0f : v.y;
        v.z = (v.z == -INFINITY) ? 0.0f : v.z;
        v.w = (v.w == -INFINITY) ? 0.0f : v.w;
        out[i] = v;
    }
    if (blockIdx.x == 0 && threadIdx.x == 0) {
        scalar_slot[0] = (float)(feat_depth[0] + 1);
    }
}

extern "C" void kernel_launch(void* const* d_in, const int* in_sizes, int n_in,
                              void* d_out, int out_size, void* d_ws, size_t ws_size,
                              hipStream_t stream) {
    const float* feat       = (const float*)d_in[0];
    const int*   src_ids    = (const int*)d_in[1];
    const int*   tgt_ids    = (const int*)d_in[2];
    const int*   ntypes     = (const int*)d_in[3];
    const int*   feat_depth = (const int*)d_in[5];
    float* out = (float*)d_out;

    const int E = in_sizes[1];              // 4194304
    const int nout_elems = out_size - 1;    // N_OUT * 64
    const int n4 = nout_elems / 4;

    // 1) init output to -inf
    fill_neginf_kernel<<<2048, 256, 0, stream>>>((float4*)out, n4);

    // 2) masked atomic scatter-max (16 threads / edge, float4 per thread)
    long long total = (long long)E * 16;
    int blocks = (int)((total + 255) / 256);
    scatter_max_kernel<<<blocks, 256, 0, stream>>>(
        (const float4*)feat, src_ids, tgt_ids, ntypes, out, E);

    // 3) -inf -> 0 for empty segments, and write feat_depth+1 scalar
    finalize_kernel<<<2048, 256, 0, stream>>>(
        (float4*)out, n4, feat_depth, out + nout_elems);
}

// Round 2
// 464.863 us; speedup vs baseline: 8.3729x; 8.3729x over previous
//
#include <hip/hip_runtime.h>
#include <math.h>

#define CCH 64
#define SCAN_CHUNK 2048   // elements per scan1 block (256 thr * 8)
#define MAXB 1024         // max scan blocks scan2 can handle

// ---------------- fallback (round-1 atomic path) ----------------

__device__ __forceinline__ void atomicMaxF(float* addr, float v) {
    if (v >= 0.0f) atomicMax((int*)addr, __float_as_int(v));
    else           atomicMin((unsigned int*)addr, __float_as_uint(v));
}

__global__ __launch_bounds__(256) void fill_neginf_kernel(float4* out, int n4) {
    int i = blockIdx.x * blockDim.x + threadIdx.x;
    int stride = gridDim.x * blockDim.x;
    const float4 v = make_float4(-INFINITY, -INFINITY, -INFINITY, -INFINITY);
    for (; i < n4; i += stride) out[i] = v;
}

__global__ __launch_bounds__(256) void scatter_max_kernel(
        const float4* __restrict__ feat4, const int* __restrict__ src,
        const int* __restrict__ tgt, const int* __restrict__ ntypes,
        float* __restrict__ out, int E) {
    int gid = blockIdx.x * blockDim.x + threadIdx.x;
    int e = gid >> 4, q = gid & 15;
    if (e >= E) return;
    int n0 = ntypes[e*3+0], n1 = ntypes[e*3+1], n2 = ntypes[e*3+2];
    if ((n0 | n1 | n2) < 0) return;
    float4 f = feat4[(size_t)tgt[e] * 16 + q];
    float* o = out + (size_t)src[e] * CCH + q * 4;
    atomicMaxF(o+0, f.x); atomicMaxF(o+1, f.y);
    atomicMaxF(o+2, f.z); atomicMaxF(o+3, f.w);
}

__global__ __launch_bounds__(256) void finalize_kernel(
        float4* out, int n4, const int* feat_depth, float* scalar_slot) {
    int i = blockIdx.x * blockDim.x + threadIdx.x;
    int stride = gridDim.x * blockDim.x;
    for (; i < n4; i += stride) {
        float4 v = out[i];
        v.x = (v.x == -INFINITY) ? 0.0f : v.x;
        v.y = (v.y == -INFINITY) ? 0.0f : v.y;
        v.z = (v.z == -INFINITY) ? 0.0f : v.z;
        v.w = (v.w == -INFINITY) ? 0.0f : v.w;
        out[i] = v;
    }
    if (blockIdx.x == 0 && threadIdx.x == 0)
        scalar_slot[0] = (float)(feat_depth[0] + 1);
}

// ---------------- CSR gather path ----------------

__global__ __launch_bounds__(256) void zero_kernel(int* p, int n) {
    int i = blockIdx.x * blockDim.x + threadIdx.x;
    int stride = gridDim.x * blockDim.x;
    for (; i < n; i += stride) p[i] = 0;
}

// histogram of passing edges by src
__global__ __launch_bounds__(256) void count_kernel(
        const int* __restrict__ src, const int* __restrict__ ntypes,
        int* __restrict__ counts, int E) {
    int e = blockIdx.x * blockDim.x + threadIdx.x;
    if (e >= E) return;
    int n0 = ntypes[e*3+0], n1 = ntypes[e*3+1], n2 = ntypes[e*3+2];
    if ((n0 | n1 | n2) < 0) return;
    atomicAdd(&counts[src[e]], 1);
}

// per-chunk exclusive scan; chunk totals to bsums
__global__ __launch_bounds__(256) void scan1_kernel(
        const int* __restrict__ counts, int* __restrict__ off,
        int* __restrict__ bsums, int N) {
    __shared__ int lds[256];
    int b = blockIdx.x, t = threadIdx.x;
    int base = b * SCAN_CHUNK + t * 8;
    int v[8]; int s = 0;
    #pragma unroll
    for (int i = 0; i < 8; ++i) {
        int idx = base + i;
        v[i] = (idx < N) ? counts[idx] : 0;
        s += v[i];
    }
    lds[t] = s;
    __syncthreads();
    for (int o = 1; o < 256; o <<= 1) {
        int x = (t >= o) ? lds[t - o] : 0;
        __syncthreads();
        lds[t] += x;
        __syncthreads();
    }
    int excl = lds[t] - s;
    if (t == 255) bsums[b] = lds[255];
    int run = excl;
    #pragma unroll
    for (int i = 0; i < 8; ++i) {
        int idx = base + i;
        if (idx < N) off[idx] = run;
        run += v[i];
    }
}

// exclusive scan of block sums (nb <= 1024), single block
__global__ __launch_bounds__(1024) void scan2_kernel(int* bsums, int nb) {
    __shared__ int lds[1024];
    int t = threadIdx.x;
    lds[t] = (t < nb) ? bsums[t] : 0;
    __syncthreads();
    for (int o = 1; o < 1024; o <<= 1) {
        int x = (t >= o) ? lds[t - o] : 0;
        __syncthreads();
        lds[t] += x;
        __syncthreads();
    }
    if (t < nb) bsums[t] = (t == 0) ? 0 : lds[t - 1];
}

// add chunk bases; init cursor = offset
__global__ __launch_bounds__(256) void scan3_kernel(
        int* __restrict__ off, int* __restrict__ cur,
        const int* __restrict__ bsums, int N) {
    int i = blockIdx.x * blockDim.x + threadIdx.x;
    int stride = gridDim.x * blockDim.x;
    for (; i < N; i += stride) {
        int o = off[i] + bsums[i / SCAN_CHUNK];
        off[i] = o;
        cur[i] = o;
    }
}

// bucket-fill target ids per src row
__global__ __launch_bounds__(256) void fill_edges_kernel(
        const int* __restrict__ src, const int* __restrict__ tgt,
        const int* __restrict__ ntypes, int* __restrict__ cur,
        int* __restrict__ edgeTgt, int E) {
    int e = blockIdx.x * blockDim.x + threadIdx.x;
    if (e >= E) return;
    int n0 = ntypes[e*3+0], n1 = ntypes[e*3+1], n2 = ntypes[e*3+2];
    if ((n0 | n1 | n2) < 0) return;
    int pos = atomicAdd(&cur[src[e]], 1);
    edgeTgt[pos] = tgt[e];
}

// one 16-lane group per output row: gather feat rows, register max, one write
__global__ __launch_bounds__(256) void gather_max_kernel(
        const float4* __restrict__ feat4, const int* __restrict__ off,
        const int* __restrict__ cur, const int* __restrict__ edgeTgt,
        float4* __restrict__ out4, int N,
        const int* __restrict__ feat_depth, float* __restrict__ scalar_slot) {
    int gid = blockIdx.x * blockDim.x + threadIdx.x;
    if (gid == 0) scalar_slot[0] = (float)(feat_depth[0] + 1);
    int r = gid >> 4, q = gid & 15;
    if (r >= N) return;
    int beg = off[r], end = cur[r];
    float4 acc = make_float4(0.0f, 0.0f, 0.0f, 0.0f);  // empty rows -> 0
    if (beg < end) {
        int t0 = edgeTgt[beg];
        float4 f = feat4[(size_t)t0 * 16 + q];
        acc = f;
        for (int j = beg + 1; j < end; ++j) {
            int t = edgeTgt[j];
            f = feat4[(size_t)t * 16 + q];
            acc.x = fmaxf(acc.x, f.x);
            acc.y = fmaxf(acc.y, f.y);
            acc.z = fmaxf(acc.z, f.z);
            acc.w = fmaxf(acc.w, f.w);
        }
    }
    out4[(size_t)r * 16 + q] = acc;
}

extern "C" void kernel_launch(void* const* d_in, const int* in_sizes, int n_in,
                              void* d_out, int out_size, void* d_ws, size_t ws_size,
                              hipStream_t stream) {
    const float* feat       = (const float*)d_in[0];
    const int*   src_ids    = (const int*)d_in[1];
    const int*   tgt_ids    = (const int*)d_in[2];
    const int*   ntypes     = (const int*)d_in[3];
    const int*   feat_depth = (const int*)d_in[5];
    float* out = (float*)d_out;

    const int E = in_sizes[1];
    const int nout_elems = out_size - 1;
    const int N = nout_elems / CCH;      // output rows
    const int n4 = nout_elems / 4;

    const int nScanBlocks = (N + SCAN_CHUNK - 1) / SCAN_CHUNK;

    // ws layout (ints): counts[N] | off[N] | cur[N] | bsums[MAXB] | edgeTgt[E]
    size_t need = ((size_t)N * 3 + MAXB + (size_t)E) * sizeof(int);

    if (ws_size < need || nScanBlocks > MAXB) {
        // fallback: atomic scatter-max
        fill_neginf_kernel<<<2048, 256, 0, stream>>>((float4*)out, n4);
        long long total = (long long)E * 16;
        int blocks = (int)((total + 255) / 256);
        scatter_max_kernel<<<blocks, 256, 0, stream>>>(
            (const float4*)feat, src_ids, tgt_ids, ntypes, out, E);
        finalize_kernel<<<2048, 256, 0, stream>>>(
            (float4*)out, n4, feat_depth, out + nout_elems);
        return;
    }

    int* counts  = (int*)d_ws;
    int* off     = counts + N;
    int* cur     = off + N;
    int* bsums   = cur + N;
    int* edgeTgt = bsums + MAXB;

    int eBlocks = (E + 255) / 256;

    zero_kernel<<<2048, 256, 0, stream>>>(counts, N);
    count_kernel<<<eBlocks, 256, 0, stream>>>(src_ids, ntypes, counts, E);
    scan1_kernel<<<nScanBlocks, 256, 0, stream>>>(counts, off, bsums, N);
    scan2_kernel<<<1, 1024, 0, stream>>>(bsums, nScanBlocks);
    scan3_kernel<<<2048, 256, 0, stream>>>(off, cur, bsums, N);
    fill_edges_kernel<<<eBlocks, 256, 0, stream>>>(
        src_ids, tgt_ids, ntypes, cur, edgeTgt, E);

    long long gthreads = (long long)N * 16;
    int gBlocks = (int)((gthreads + 255) / 256);
    gather_max_kernel<<<gBlocks, 256, 0, stream>>>(
        (const float4*)feat, off, cur, edgeTgt, (float4*)out, N,
        feat_depth, out + nout_elems);
}

// Round 3
// 448.860 us; speedup vs baseline: 8.6714x; 1.0357x over previous
//
#include <hip/hip_runtime.h>
#include <math.h>

#define CCH 64
#define SCAN_CHUNK 2048   // elements per scan1 block (256 thr * 8)
#define MAXB 1024         // max scan blocks scan2 can handle
#define EPT 8             // edges per thread in edge passes

// ---------------- fallback (round-1 atomic path) ----------------

__device__ __forceinline__ void atomicMaxF(float* addr, float v) {
    if (v >= 0.0f) atomicMax((int*)addr, __float_as_int(v));
    else           atomicMin((unsigned int*)addr, __float_as_uint(v));
}

__global__ __launch_bounds__(256) void fill_neginf_kernel(float4* out, int n4) {
    int i = blockIdx.x * blockDim.x + threadIdx.x;
    int stride = gridDim.x * blockDim.x;
    const float4 v = make_float4(-INFINITY, -INFINITY, -INFINITY, -INFINITY);
    for (; i < n4; i += stride) out[i] = v;
}

__global__ __launch_bounds__(256) void scatter_max_kernel(
        const float4* __restrict__ feat4, const int* __restrict__ src,
        const int* __restrict__ tgt, const int* __restrict__ ntypes,
        float* __restrict__ out, int E) {
    int gid = blockIdx.x * blockDim.x + threadIdx.x;
    int e = gid >> 4, q = gid & 15;
    if (e >= E) return;
    int n0 = ntypes[e*3+0], n1 = ntypes[e*3+1], n2 = ntypes[e*3+2];
    if ((n0 | n1 | n2) < 0) return;
    float4 f = feat4[(size_t)tgt[e] * 16 + q];
    float* o = out + (size_t)src[e] * CCH + q * 4;
    atomicMaxF(o+0, f.x); atomicMaxF(o+1, f.y);
    atomicMaxF(o+2, f.z); atomicMaxF(o+3, f.w);
}

__global__ __launch_bounds__(256) void finalize_kernel(
        float4* out, int n4, const int* feat_depth, float* scalar_slot) {
    int i = blockIdx.x * blockDim.x + threadIdx.x;
    int stride = gridDim.x * blockDim.x;
    for (; i < n4; i += stride) {
        float4 v = out[i];
        v.x = (v.x == -INFINITY) ? 0.0f : v.x;
        v.y = (v.y == -INFINITY) ? 0.0f : v.y;
        v.z = (v.z == -INFINITY) ? 0.0f : v.z;
        v.w = (v.w == -INFINITY) ? 0.0f : v.w;
        out[i] = v;
    }
    if (blockIdx.x == 0 && threadIdx.x == 0)
        scalar_slot[0] = (float)(feat_depth[0] + 1);
}

// ---------------- CSR gather path ----------------

__global__ __launch_bounds__(256) void zero_kernel(int4* p, int n4) {
    int i = blockIdx.x * blockDim.x + threadIdx.x;
    int stride = gridDim.x * blockDim.x;
    const int4 z = make_int4(0, 0, 0, 0);
    for (; i < n4; i += stride) p[i] = z;
}

// histogram of passing edges by src — 8 edges/thread, int4 loads
__global__ __launch_bounds__(256) void count8_kernel(
        const int* __restrict__ src, const int* __restrict__ ntypes,
        int* __restrict__ counts, int E) {
    long long e0 = (long long)(blockIdx.x * blockDim.x + threadIdx.x) * EPT;
    if (e0 >= E) return;
    if (e0 + EPT <= E) {
        union { int4 v[2]; int a[8]; } sv;
        const int4* s4 = (const int4*)(src + e0);
        sv.v[0] = s4[0]; sv.v[1] = s4[1];
        union { int4 v[6]; int a[24]; } nt;
        const int4* n4p = (const int4*)(ntypes + e0 * 3);
        #pragma unroll
        for (int i = 0; i < 6; ++i) nt.v[i] = n4p[i];
        #pragma unroll
        for (int i = 0; i < EPT; ++i) {
            if ((nt.a[3*i] | nt.a[3*i+1] | nt.a[3*i+2]) >= 0)
                atomicAdd(&counts[sv.a[i]], 1);
        }
    } else {
        for (long long e = e0; e < E; ++e) {
            if ((ntypes[e*3] | ntypes[e*3+1] | ntypes[e*3+2]) >= 0)
                atomicAdd(&counts[src[e]], 1);
        }
    }
}

// per-chunk exclusive scan; chunk totals to bsums
__global__ __launch_bounds__(256) void scan1_kernel(
        const int* __restrict__ counts, int* __restrict__ off,
        int* __restrict__ bsums, int N) {
    __shared__ int lds[256];
    int b = blockIdx.x, t = threadIdx.x;
    int base = b * SCAN_CHUNK + t * 8;
    int v[8]; int s = 0;
    #pragma unroll
    for (int i = 0; i < 8; ++i) {
        int idx = base + i;
        v[i] = (idx < N) ? counts[idx] : 0;
        s += v[i];
    }
    lds[t] = s;
    __syncthreads();
    for (int o = 1; o < 256; o <<= 1) {
        int x = (t >= o) ? lds[t - o] : 0;
        __syncthreads();
        lds[t] += x;
        __syncthreads();
    }
    int excl = lds[t] - s;
    if (t == 255) bsums[b] = lds[255];
    int run = excl;
    #pragma unroll
    for (int i = 0; i < 8; ++i) {
        int idx = base + i;
        if (idx < N) off[idx] = run;
        run += v[i];
    }
}

// exclusive scan of block sums (nb <= 1024), single block
__global__ __launch_bounds__(1024) void scan2_kernel(int* bsums, int nb) {
    __shared__ int lds[1024];
    int t = threadIdx.x;
    lds[t] = (t < nb) ? bsums[t] : 0;
    __syncthreads();
    for (int o = 1; o < 1024; o <<= 1) {
        int x = (t >= o) ? lds[t - o] : 0;
        __syncthreads();
        lds[t] += x;
        __syncthreads();
    }
    if (t < nb) bsums[t] = (t == 0) ? 0 : lds[t - 1];
}

// add chunk bases to off (int4 vectorized; SCAN_CHUNK % 4 == 0)
__global__ __launch_bounds__(256) void scan3_kernel(
        int4* __restrict__ off4, const int* __restrict__ bsums, int N4) {
    int i = blockIdx.x * blockDim.x + threadIdx.x;
    int stride = gridDim.x * blockDim.x;
    for (; i < N4; i += stride) {
        int base = bsums[(i * 4) / SCAN_CHUNK];
        int4 o = off4[i];
        o.x += base; o.y += base; o.z += base; o.w += base;
        off4[i] = o;
    }
}

// bucket-fill target ids per src row — 8 edges/thread, advances off in place
__global__ __launch_bounds__(256) void fill8_kernel(
        const int* __restrict__ src, const int* __restrict__ tgt,
        const int* __restrict__ ntypes, int* __restrict__ off,
        int* __restrict__ edgeTgt, int E) {
    long long e0 = (long long)(blockIdx.x * blockDim.x + threadIdx.x) * EPT;
    if (e0 >= E) return;
    if (e0 + EPT <= E) {
        union { int4 v[2]; int a[8]; } sv, tv;
        const int4* s4 = (const int4*)(src + e0);
        const int4* t4 = (const int4*)(tgt + e0);
        sv.v[0] = s4[0]; sv.v[1] = s4[1];
        tv.v[0] = t4[0]; tv.v[1] = t4[1];
        union { int4 v[6]; int a[24]; } nt;
        const int4* n4p = (const int4*)(ntypes + e0 * 3);
        #pragma unroll
        for (int i = 0; i < 6; ++i) nt.v[i] = n4p[i];
        // independent atomic+store chains — latencies overlap
        #pragma unroll
        for (int i = 0; i < EPT; ++i) {
            if ((nt.a[3*i] | nt.a[3*i+1] | nt.a[3*i+2]) >= 0) {
                int pos = atomicAdd(&off[sv.a[i]], 1);
                edgeTgt[pos] = tv.a[i];
            }
        }
    } else {
        for (long long e = e0; e < E; ++e) {
            if ((ntypes[e*3] | ntypes[e*3+1] | ntypes[e*3+2]) >= 0) {
                int pos = atomicAdd(&off[src[e]], 1);
                edgeTgt[pos] = tgt[e];
            }
        }
    }
}

__device__ __forceinline__ float4 max4f(float4 a, float4 b) {
    return make_float4(fmaxf(a.x, b.x), fmaxf(a.y, b.y),
                       fmaxf(a.z, b.z), fmaxf(a.w, b.w));
}

// one 16-lane group per output row; ×4 unrolled gather for memory ILP
__global__ __launch_bounds__(256) void gather_max_kernel(
        const float4* __restrict__ feat4, const int* __restrict__ off_end,
        const int* __restrict__ counts, const int* __restrict__ edgeTgt,
        float4* __restrict__ out4, int N,
        const int* __restrict__ feat_depth, float* __restrict__ scalar_slot) {
    int gid = blockIdx.x * blockDim.x + threadIdx.x;
    if (gid == 0) scalar_slot[0] = (float)(feat_depth[0] + 1);
    int r = gid >> 4, q = gid & 15;
    if (r >= N) return;
    int end = off_end[r];
    int cnt = counts[r];
    int beg = end - cnt;
    float4 acc = make_float4(-INFINITY, -INFINITY, -INFINITY, -INFINITY);
    int j = beg;
    for (; j + 4 <= end; j += 4) {
        int t0 = edgeTgt[j+0], t1 = edgeTgt[j+1];
        int t2 = edgeTgt[j+2], t3 = edgeTgt[j+3];
        float4 f0 = feat4[(size_t)t0 * 16 + q];
        float4 f1 = feat4[(size_t)t1 * 16 + q];
        float4 f2 = feat4[(size_t)t2 * 16 + q];
        float4 f3 = feat4[(size_t)t3 * 16 + q];
        acc = max4f(acc, max4f(max4f(f0, f1), max4f(f2, f3)));
    }
    for (; j < end; ++j) {
        int t = edgeTgt[j];
        acc = max4f(acc, feat4[(size_t)t * 16 + q]);
    }
    if (cnt == 0) acc = make_float4(0.0f, 0.0f, 0.0f, 0.0f);
    out4[(size_t)r * 16 + q] = acc;
}

extern "C" void kernel_launch(void* const* d_in, const int* in_sizes, int n_in,
                              void* d_out, int out_size, void* d_ws, size_t ws_size,
                              hipStream_t stream) {
    const float* feat       = (const float*)d_in[0];
    const int*   src_ids    = (const int*)d_in[1];
    const int*   tgt_ids    = (const int*)d_in[2];
    const int*   ntypes     = (const int*)d_in[3];
    const int*   feat_depth = (const int*)d_in[5];
    float* out = (float*)d_out;

    const int E = in_sizes[1];
    const int nout_elems = out_size - 1;
    const int N = nout_elems / CCH;      // output rows
    const int n4 = nout_elems / 4;

    const int nScanBlocks = (N + SCAN_CHUNK - 1) / SCAN_CHUNK;

    // ws layout (ints): counts[N] | off[N] | bsums[MAXB] | edgeTgt[E]
    size_t need = ((size_t)N * 2 + MAXB + (size_t)E) * sizeof(int);

    if (ws_size < need || nScanBlocks > MAXB || (N % 4) != 0) {
        fill_neginf_kernel<<<2048, 256, 0, stream>>>((float4*)out, n4);
        long long total = (long long)E * 16;
        int blocks = (int)((total + 255) / 256);
        scatter_max_kernel<<<blocks, 256, 0, stream>>>(
            (const float4*)feat, src_ids, tgt_ids, ntypes, out, E);
        finalize_kernel<<<2048, 256, 0, stream>>>(
            (float4*)out, n4, feat_depth, out + nout_elems);
        return;
    }

    int* counts  = (int*)d_ws;
    int* off     = counts + N;
    int* bsums   = off + N;
    int* edgeTgt = bsums + MAXB;

    long long eThreads = ((long long)E + EPT - 1) / EPT;
    int eBlocks = (int)((eThreads + 255) / 256);

    zero_kernel<<<512, 256, 0, stream>>>((int4*)counts, N / 4);
    count8_kernel<<<eBlocks, 256, 0, stream>>>(src_ids, ntypes, counts, E);
    scan1_kernel<<<nScanBlocks, 256, 0, stream>>>(counts, off, bsums, N);
    scan2_kernel<<<1, 1024, 0, stream>>>(bsums, nScanBlocks);
    scan3_kernel<<<1024, 256, 0, stream>>>((int4*)off, bsums, N / 4);
    fill8_kernel<<<eBlocks, 256, 0, stream>>>(
        src_ids, tgt_ids, ntypes, off, edgeTgt, E);

    long long gthreads = (long long)N * 16;
    int gBlocks = (int)((gthreads + 255) / 256);
    gather_max_kernel<<<gBlocks, 256, 0, stream>>>(
        (const float4*)feat, off, counts, edgeTgt, (float4*)out, N,
        feat_depth, out + nout_elems);
}

// Round 4
// 311.098 us; speedup vs baseline: 12.5113x; 1.4428x over previous
//
#include <hip/hip_runtime.h>
#include <math.h>

#define CCH 64
#define EPT 8              // edges per thread in the deposit pass
#define SPILL_CAP_MAX 262144

typedef float f4v __attribute__((ext_vector_type(4)));

__device__ __forceinline__ void nt_store_f4(float4 v, float4* p) {
    f4v x; x.x = v.x; x.y = v.y; x.z = v.z; x.w = v.w;
    __builtin_nontemporal_store(x, (f4v*)p);
}

__device__ __forceinline__ float4 max4f(float4 a, float4 b) {
    return make_float4(fmaxf(a.x, b.x), fmaxf(a.y, b.y),
                       fmaxf(a.z, b.z), fmaxf(a.w, b.w));
}

__device__ __forceinline__ void atomicMaxF(float* addr, float v) {
    if (v >= 0.0f) atomicMax((int*)addr, __float_as_int(v));
    else           atomicMin((unsigned int*)addr, __float_as_uint(v));
}

// ---------------- last-resort fallback (round-1 atomic path) ----------------

__global__ __launch_bounds__(256) void fill_neginf_kernel(float4* out, int n4) {
    int i = blockIdx.x * blockDim.x + threadIdx.x;
    int stride = gridDim.x * blockDim.x;
    const float4 v = make_float4(-INFINITY, -INFINITY, -INFINITY, -INFINITY);
    for (; i < n4; i += stride) out[i] = v;
}

__global__ __launch_bounds__(256) void scatter_max_kernel(
        const float4* __restrict__ feat4, const int* __restrict__ src,
        const int* __restrict__ tgt, const int* __restrict__ ntypes,
        float* __restrict__ out, int E) {
    int gid = blockIdx.x * blockDim.x + threadIdx.x;
    int e = gid >> 4, q = gid & 15;
    if (e >= E) return;
    int n0 = ntypes[e*3+0], n1 = ntypes[e*3+1], n2 = ntypes[e*3+2];
    if ((n0 | n1 | n2) < 0) return;
    float4 f = feat4[(size_t)tgt[e] * 16 + q];
    float* o = out + (size_t)src[e] * CCH + q * 4;
    atomicMaxF(o+0, f.x); atomicMaxF(o+1, f.y);
    atomicMaxF(o+2, f.z); atomicMaxF(o+3, f.w);
}

__global__ __launch_bounds__(256) void finalize_kernel(
        float4* out, int n4, const int* feat_depth, float* scalar_slot) {
    int i = blockIdx.x * blockDim.x + threadIdx.x;
    int stride = gridDim.x * blockDim.x;
    for (; i < n4; i += stride) {
        float4 v = out[i];
        v.x = (v.x == -INFINITY) ? 0.0f : v.x;
        v.y = (v.y == -INFINITY) ? 0.0f : v.y;
        v.z = (v.z == -INFINITY) ? 0.0f : v.z;
        v.w = (v.w == -INFINITY) ? 0.0f : v.w;
        out[i] = v;
    }
    if (blockIdx.x == 0 && threadIdx.x == 0)
        scalar_slot[0] = (float)(feat_depth[0] + 1);
}

// ---------------- padded-bucket path ----------------

__global__ __launch_bounds__(256) void zero4_kernel(int4* p, long long n4) {
    long long i = blockIdx.x * (long long)blockDim.x + threadIdx.x;
    long long stride = gridDim.x * (long long)blockDim.x;
    const int4 z = make_int4(0, 0, 0, 0);
    for (; i < n4; i += stride) p[i] = z;
}

// Single edge pass: mask-check, count via returning atomic, NT-store deposit.
template <int STRIDE>
__global__ __launch_bounds__(256) void fill_deposit_kernel(
        const int* __restrict__ src, const int* __restrict__ tgt,
        const int* __restrict__ ntypes, int* __restrict__ buckets,
        unsigned long long* __restrict__ spill, int spillCap,
        int* __restrict__ spillCur, int E) {
    constexpr int K = STRIDE - 1;
    long long e0 = (long long)(blockIdx.x * blockDim.x + threadIdx.x) * EPT;
    if (e0 >= E) return;
    if (e0 + EPT <= E) {
        union { int4 v[2]; int a[8]; } sv, tv;
        const int4* s4 = (const int4*)(src + e0);
        const int4* t4 = (const int4*)(tgt + e0);
        sv.v[0] = s4[0]; sv.v[1] = s4[1];
        tv.v[0] = t4[0]; tv.v[1] = t4[1];
        union { int4 v[6]; int a[24]; } nt;
        const int4* n4p = (const int4*)(ntypes + e0 * 3);
        #pragma unroll
        for (int i = 0; i < 6; ++i) nt.v[i] = n4p[i];
        #pragma unroll
        for (int i = 0; i < EPT; ++i) {
            if ((nt.a[3*i] | nt.a[3*i+1] | nt.a[3*i+2]) >= 0) {
                int r = sv.a[i], t = tv.a[i];
                int* b = buckets + (size_t)r * STRIDE;
                int c = atomicAdd(b, 1);
                if (c < K) {
                    __builtin_nontemporal_store(t, b + 1 + c);
                } else {
                    int sp = atomicAdd(spillCur, 1);
                    if (sp < spillCap) {
                        unsigned long long pk =
                            ((unsigned long long)(unsigned)r << 32) | (unsigned)t;
                        __builtin_nontemporal_store(pk, &spill[sp]);
                    }
                }
            }
        }
    } else {
        for (long long e = e0; e < E; ++e) {
            if ((ntypes[e*3] | ntypes[e*3+1] | ntypes[e*3+2]) >= 0) {
                int r = src[e], t = tgt[e];
                int* b = buckets + (size_t)r * STRIDE;
                int c = atomicAdd(b, 1);
                if (c < K) {
                    __builtin_nontemporal_store(t, b + 1 + c);
                } else {
                    int sp = atomicAdd(spillCur, 1);
                    if (sp < spillCap) {
                        unsigned long long pk =
                            ((unsigned long long)(unsigned)r << 32) | (unsigned)t;
                        __builtin_nontemporal_store(pk, &spill[sp]);
                    }
                }
            }
        }
    }
}

// One 16-lane group per row: whole bucket line -> registers, then clamped
// fully-unrolled gathers in quads (4-wide memory ILP, static reg indexing).
template <int STRIDE>
__global__ __launch_bounds__(256) void gather_bucket_kernel(
        const float4* __restrict__ feat4, const int* __restrict__ buckets,
        float4* __restrict__ out4, int N,
        const int* __restrict__ feat_depth, float* __restrict__ scalar_slot) {
    constexpr int K = STRIDE - 1;
    int gid = blockIdx.x * blockDim.x + threadIdx.x;
    if (gid == 0) scalar_slot[0] = (float)(feat_depth[0] + 1);
    int r = gid >> 4, q = gid & 15;
    if (r >= N) return;
    const int* b = buckets + (size_t)r * STRIDE;
    int va[STRIDE];
    #pragma unroll
    for (int w = 0; w < STRIDE / 4; ++w) {
        int4 x = ((const int4*)b)[w];
        va[4*w+0] = x.x; va[4*w+1] = x.y; va[4*w+2] = x.z; va[4*w+3] = x.w;
    }
    int cnt = va[0];
    int m = cnt < K ? cnt : K;            // valid slots are 1..m
    float4 acc;
    if (m <= 0) {
        acc = make_float4(0.0f, 0.0f, 0.0f, 0.0f);
    } else {
        int t0 = va[1];
        acc = feat4[(size_t)t0 * 16 + q];
        #pragma unroll
        for (int base = 2; base <= K; base += 4) {
            if (base <= m) {
                #pragma unroll
                for (int s = base; s < base + 4; ++s) {
                    if (s <= K) {
                        int t = (s <= m) ? va[s] : t0;   // clamped dup -> L1 hit
                        acc = max4f(acc, feat4[(size_t)t * 16 + q]);
                    }
                }
            }
        }
    }
    nt_store_f4(acc, out4 + (size_t)r * 16 + q);
}

// Resolve spilled edges (rare): atomic max on top of gather output (only raises).
__global__ __launch_bounds__(256) void spill_kernel(
        const float4* __restrict__ feat4,
        const unsigned long long* __restrict__ spill,
        const int* __restrict__ spillCur, int spillCap,
        float* __restrict__ out) {
    int n = *spillCur; if (n > spillCap) n = spillCap;
    long long total = (long long)n * 16;
    long long stride = (long long)gridDim.x * blockDim.x;
    for (long long i = blockIdx.x * (long long)blockDim.x + threadIdx.x;
         i < total; i += stride) {
        int e = (int)(i >> 4), q = (int)(i & 15);
        unsigned long long pk = spill[e];
        int r = (int)(pk >> 32);
        int t = (int)(pk & 0xffffffffu);
        float4 f = feat4[(size_t)t * 16 + q];
        float* o = out + (size_t)r * CCH + q * 4;
        atomicMaxF(o+0, f.x); atomicMaxF(o+1, f.y);
        atomicMaxF(o+2, f.z); atomicMaxF(o+3, f.w);
    }
}

// If the spill list overflowed (never expected), rescan ALL edges with atomic
// max — idempotent and only raises values, so it is correct on top of gather.
__global__ __launch_bounds__(256) void repair_kernel(
        const float4* __restrict__ feat4, const int* __restrict__ src,
        const int* __restrict__ tgt, const int* __restrict__ ntypes,
        const int* __restrict__ spillCur, int spillCap,
        float* __restrict__ out, int E) {
    if (*spillCur <= spillCap) return;
    long long total = (long long)E * 16;
    long long stride = (long long)gridDim.x * blockDim.x;
    for (long long i = blockIdx.x * (long long)blockDim.x + threadIdx.x;
         i < total; i += stride) {
        int e = (int)(i >> 4), q = (int)(i & 15);
        if ((ntypes[e*3] | ntypes[e*3+1] | ntypes[e*3+2]) < 0) continue;
        float4 f = feat4[(size_t)tgt[e] * 16 + q];
        float* o = out + (size_t)src[e] * CCH + q * 4;
        atomicMaxF(o+0, f.x); atomicMaxF(o+1, f.y);
        atomicMaxF(o+2, f.z); atomicMaxF(o+3, f.w);
    }
}

extern "C" void kernel_launch(void* const* d_in, const int* in_sizes, int n_in,
                              void* d_out, int out_size, void* d_ws, size_t ws_size,
                              hipStream_t stream) {
    const float* feat       = (const float*)d_in[0];
    const int*   src_ids    = (const int*)d_in[1];
    const int*   tgt_ids    = (const int*)d_in[2];
    const int*   ntypes     = (const int*)d_in[3];
    const int*   feat_depth = (const int*)d_in[5];
    float* out = (float*)d_out;

    const int E = in_sizes[1];
    const int nout_elems = out_size - 1;
    const int N = nout_elems / CCH;      // output rows
    const int n4 = nout_elems / 4;

    // pick the largest bucket stride that fits the workspace
    size_t wsInts = ws_size / sizeof(int);
    int stride = 0;
    for (int s = 16; s >= 8; s -= 4) {
        size_t need = (size_t)N * s + 16 + 2ull * 4096;  // buckets + cursor + min spill
        if (need <= wsInts) { stride = s; break; }
    }

    if (stride == 0) {
        // last-resort: atomic scatter-max
        fill_neginf_kernel<<<2048, 256, 0, stream>>>((float4*)out, n4);
        long long total = (long long)E * 16;
        int blocks = (int)((total + 255) / 256);
        scatter_max_kernel<<<blocks, 256, 0, stream>>>(
            (const float4*)feat, src_ids, tgt_ids, ntypes, out, E);
        finalize_kernel<<<2048, 256, 0, stream>>>(
            (float4*)out, n4, feat_depth, out + nout_elems);
        return;
    }

    int* buckets  = (int*)d_ws;
    int* spillCur = buckets + (size_t)N * stride;          // 16-int block, [0]=cursor
    unsigned long long* spill = (unsigned long long*)(spillCur + 16);
    size_t rem = wsInts - (size_t)N * stride - 16;
    long long scap = (long long)(rem / 2);
    if (scap > SPILL_CAP_MAX) scap = SPILL_CAP_MAX;
    int spillCap = (int)scap;

    long long zn4 = ((long long)N * stride + 16) / 4;
    zero4_kernel<<<2048, 256, 0, stream>>>((int4*)d_ws, zn4);

    long long eThreads = ((long long)E + EPT - 1) / EPT;
    int eBlocks = (int)((eThreads + 255) / 256);
    long long gthreads = (long long)N * 16;
    int gBlocks = (int)((gthreads + 255) / 256);

    if (stride == 16) {
        fill_deposit_kernel<16><<<eBlocks, 256, 0, stream>>>(
            src_ids, tgt_ids, ntypes, buckets, spill, spillCap, spillCur, E);
        gather_bucket_kernel<16><<<gBlocks, 256, 0, stream>>>(
            (const float4*)feat, buckets, (float4*)out, N,
            feat_depth, out + nout_elems);
    } else if (stride == 12) {
        fill_deposit_kernel<12><<<eBlocks, 256, 0, stream>>>(
            src_ids, tgt_ids, ntypes, buckets, spill, spillCap, spillCur, E);
        gather_bucket_kernel<12><<<gBlocks, 256, 0, stream>>>(
            (const float4*)feat, buckets, (float4*)out, N,
            feat_depth, out + nout_elems);
    } else {
        fill_deposit_kernel<8><<<eBlocks, 256, 0, stream>>>(
            src_ids, tgt_ids, ntypes, buckets, spill, spillCap, spillCur, E);
        gather_bucket_kernel<8><<<gBlocks, 256, 0, stream>>>(
            (const float4*)feat, buckets, (float4*)out, N,
            feat_depth, out + nout_elems);
    }

    spill_kernel<<<2048, 256, 0, stream>>>(
        (const float4*)feat, spill, spillCur, spillCap, out);
    repair_kernel<<<4096, 256, 0, stream>>>(
        (const float4*)feat, src_ids, tgt_ids, ntypes,
        spillCur, spillCap, out, E);
}